// Round 1
// baseline (361.116 us; speedup 1.0000x reference)
//
#include <hip/hip_runtime.h>

// GeneralizedInteractionNet on MI355X (gfx950). R10: software-pipelined n-loop.
//
// Per layer:  M[n,D,d] = W[n,D,d]*h[n,d]
//   GEMM1: C[b,i,D] = sum_d Bi[b,i,d] * M[n,D,d]
//   GEMM2: R[b,i,D] = sum_f AT[n,i,f] * B0T[b,D,f]^T
//   out[b,n,D] = sum_i C[b,i,D]*R[b,i,D]
// i padded 40->64 (2 row tiles of 32); f padded 40->48 (3 K-steps of 16).
// Padding garbage annihilated by exact zeros in AT (rows i>=40, cols f>=40).
//
// R9 (263 us): b2=2, 2 waves/block, single-buffered per-n frags. MfmaUtil 39%
// == per-SIMD MFMA demand (71.7k cy) / wall (172.8k cy); idle = exposed L2
// latency on the 14 per-n b128 loads + per-n shfl/store tail WAR-blocking the
// next iteration (VGPR=108 -> no prefetch headroom).
// R10: b2=1, 4 waves/block (256 thr), explicit double-buffered mb/at register
// prefetch (full-iteration load->use distance), setprio(1) around MFMA
// clusters (barrier-free independent waves = m191-positive regime), packed
// f32x2 combine. Budget ~230 regs -> still 2 waves/SIMD at launch_bounds(256,2).
// Prep: B0b/B0T now built by a per-b LDS-transpose kernel (coalesced both ways)
// instead of stride-256B scalar gathers.

typedef __bf16 bf16x8 __attribute__((ext_vector_type(8)));
typedef float  f32x16 __attribute__((ext_vector_type(16)));
typedef float  f32x2  __attribute__((ext_vector_type(2)));
typedef unsigned short us4 __attribute__((ext_vector_type(4)));

constexpr int BATCH = 2048;
constexpr int FDIM  = 40;
constexpr int DDIM  = 64;
constexpr int LAY   = 3;
constexpr int IPAD  = 64;   // i padded: 2 row-tiles of 32
constexpr int FPAD  = 48;   // f padded: 3 K-steps of 16
constexpr int NSPL  = 4;    // n-loop split across 4 blocks
constexpr int NPB   = FDIM / NSPL;    // 10 n per block

__device__ __forceinline__ unsigned short f2bf(float f) {
  union { float f; unsigned u; } v; v.f = f;
  unsigned r = v.u + 0x7fff + ((v.u >> 16) & 1);   // round-to-nearest-even
  return (unsigned short)(r >> 16);
}

// M[l,n,D,d] = W*h (bf16, natural layout);
// AT[l,n,i64,f48] = alpha[l,f,i,n], zero-padded (i>=40 or f>=40 -> 0)
__global__ void prep_k(const float* __restrict__ W, const float* __restrict__ h,
                       const float* __restrict__ alpha,
                       unsigned short* __restrict__ M, unsigned short* __restrict__ AT) {
  int j = blockIdx.x * blockDim.x + threadIdx.x;
  const int nM4 = LAY * FDIM * DDIM * DDIM / 4;    // 122880
  const int nA4 = LAY * FDIM * IPAD * FPAD / 4;    // 92160
  if (j < nM4) {
    int e  = j * 4;
    int d  = e & 63;
    int ln = e >> 12;
    float4 wv = *reinterpret_cast<const float4*>(W + e);
    float4 hv = *reinterpret_cast<const float4*>(h + ln * DDIM + d);
    us4 o = { f2bf(wv.x * hv.x), f2bf(wv.y * hv.y), f2bf(wv.z * hv.z), f2bf(wv.w * hv.w) };
    *reinterpret_cast<us4*>(M + e) = o;
    return;
  }
  j -= nM4;
  if (j >= nA4) return;
  {
    int e  = j * 4;
    int f  = e % FPAD;
    int ii = (e / FPAD) % IPAD;
    int n  = (e / (FPAD * IPAD)) % FDIM;
    int l  = e / (FPAD * IPAD * FDIM);
    us4 o = {0, 0, 0, 0};
    if (ii < FDIM) {
#pragma unroll
      for (int k = 0; k < 4; ++k)
        if (f + k < FDIM)
          o[k] = f2bf(alpha[(((size_t)l * FDIM + f + k) * FDIM + ii) * FDIM + n]);
    }
    *reinterpret_cast<us4*>(AT + e) = o;
  }
}

// Per-b transpose: B0b[b,f,d] = bf16(inputs[b,f,d]) (coalesced passthrough);
// B0T[b,d,f48] = bf16(inputs[b,f,d]), f>=40 -> 0, via padded-LDS transpose.
__global__ __launch_bounds__(256) void prep_b_k(const float* __restrict__ inputs,
                                                unsigned short* __restrict__ B0b,
                                                unsigned short* __restrict__ B0T) {
  __shared__ float lds[FDIM][DDIM + 1];
  const int b = blockIdx.x;
  const float* src = inputs + (size_t)b * FDIM * DDIM;
  // 40*64 = 2560 floats = 640 float4; coalesced load, direct bf16 store of B0b.
  for (int cch = threadIdx.x; cch < FDIM * DDIM / 4; cch += 256) {
    float4 v = reinterpret_cast<const float4*>(src)[cch];
    int e = cch * 4;
    int f = e >> 6, d = e & 63;
    lds[f][d] = v.x; lds[f][d + 1] = v.y; lds[f][d + 2] = v.z; lds[f][d + 3] = v.w;
    us4 o = { f2bf(v.x), f2bf(v.y), f2bf(v.z), f2bf(v.w) };
    reinterpret_cast<us4*>(B0b + (size_t)b * FDIM * DDIM)[cch] = o;
  }
  __syncthreads();
  // B0T[b][d][f48]: 64*48 ushort = 768 us4 chunks; contiguous 8B stores.
  for (int cch = threadIdx.x; cch < DDIM * FPAD / 4; cch += 256) {
    int f4 = cch % (FPAD / 4);
    int d  = cch / (FPAD / 4);
    us4 o = {0, 0, 0, 0};
    if (f4 < FDIM / 4) {
      int f = f4 * 4;
      o[0] = f2bf(lds[f][d]);     o[1] = f2bf(lds[f + 1][d]);
      o[2] = f2bf(lds[f + 2][d]); o[3] = f2bf(lds[f + 3][d]);
    }
    reinterpret_cast<us4*>(B0T + (size_t)b * DDIM * FPAD)[cch] = o;
  }
}

// mfma_f32_32x32x16_bf16 conventions:
//   A[m=lane&31][k=8*(lane>>5)+j]  B[k=8*(lane>>5)+j][col=lane&31]
//   C/D: col=lane&31, row=(reg&3)+8*(reg>>2)+4*(lane>>5)   [HW-verified]
template <bool FINAL>
__global__ __launch_bounds__(256, 2) void layer_k(
    const unsigned short* __restrict__ Bi,   // bf16 [B][40][64] (prev layer / B0b)
    const unsigned short* __restrict__ B0T,  // bf16 [B][64][48]
    const unsigned short* __restrict__ Mt,   // [40][64][64] bf16
    const unsigned short* __restrict__ ATt,  // [40][64][48] bf16 zero-padded
    void* __restrict__ outp)                 // bf16 intermediate or f32 final
{
  const int tid  = threadIdx.x;
  const int lane = tid & 63;
  const int w    = tid >> 6;                  // wave in block (0..3)
  const int c    = lane & 31;
  const int h    = lane >> 5;
  const int nBase = (blockIdx.x & 3) * NPB;   // this block's n range
  const int b    = (blockIdx.x >> 2) * 4 + w; // one batch element per wave

  // ---- wave-constant register fragments (loaded once, reused over 10 n) ----
  // aBi[it][ks]: GEMM1 A (rows i, k=d); rows>=40 clamped (killed by R=0).
  bf16x8 aBi[2][4];
#pragma unroll
  for (int it = 0; it < 2; ++it) {
    int row = it * 32 + c; if (row > FDIM - 1) row = FDIM - 1;
#pragma unroll
    for (int ks = 0; ks < 4; ++ks)
      aBi[it][ks] = *reinterpret_cast<const bf16x8*>(
          Bi + ((size_t)b * FDIM + row) * DDIM + ks * 16 + h * 8);
  }

  // bT[dt][ks]: GEMM2 B = B0T[b][D][f], contiguous 16B per lane.
  bf16x8 bT[2][3];
#pragma unroll
  for (int dt = 0; dt < 2; ++dt)
#pragma unroll
    for (int ks = 0; ks < 3; ++ks)
      bT[dt][ks] = *reinterpret_cast<const bf16x8*>(
          B0T + ((size_t)b * DDIM + dt * 32 + c) * FPAD + ks * 16 + h * 8);

  // ---- double-buffered per-n fragments (named buffers: static indexing) ----
  bf16x8 mbA[2][4], atA[2][3], mbB[2][4], atB[2][3];

  auto loadn = [&](bf16x8 (&mb)[2][4], bf16x8 (&at)[2][3], int n) {
    const unsigned short* Mn = Mt  + n * (DDIM * DDIM);
    const unsigned short* An = ATt + n * (IPAD * FPAD);
    // mb[dt][ks]: GEMM1 B-frag. B[k=d][col=D] = M[D][d]: lane (c,h) reads
    // row D = dt*32+c, 16B chunk -- contiguous b128 from L2/L1.
#pragma unroll
    for (int dt = 0; dt < 2; ++dt)
#pragma unroll
      for (int ks = 0; ks < 4; ++ks)
        mb[dt][ks] = *reinterpret_cast<const bf16x8*>(
            Mn + (dt * 32 + c) * DDIM + ks * 16 + h * 8);
    // at[it][ks]: GEMM2 A-frag. A[m=i][k=f]: row i = it*32+c, contiguous b128.
#pragma unroll
    for (int it = 0; it < 2; ++it)
#pragma unroll
      for (int ks = 0; ks < 3; ++ks)
        at[it][ks] = *reinterpret_cast<const bf16x8*>(
            An + (it * 32 + c) * FPAD + ks * 16 + h * 8);
  };

  auto compute = [&](const bf16x8 (&mb)[2][4], const bf16x8 (&at)[2][3], int n) {
    float pout[2] = {0.f, 0.f};
#pragma unroll
    for (int it = 0; it < 2; ++it) {
#pragma unroll
      for (int dt = 0; dt < 2; ++dt) {
        f32x16 aC = {0,0,0,0,0,0,0,0,0,0,0,0,0,0,0,0};
        f32x16 aR = {0,0,0,0,0,0,0,0,0,0,0,0,0,0,0,0};
        __builtin_amdgcn_s_setprio(1);
#pragma unroll
        for (int ks = 0; ks < 4; ++ks)
          aC = __builtin_amdgcn_mfma_f32_32x32x16_bf16(aBi[it][ks], mb[dt][ks], aC, 0, 0, 0);
#pragma unroll
        for (int ks = 0; ks < 3; ++ks)
          aR = __builtin_amdgcn_mfma_f32_32x32x16_bf16(at[it][ks], bT[dt][ks], aR, 0, 0, 0);
        __builtin_amdgcn_s_setprio(0);
        // Hadamard + row-sum over this tile's 16 rows; packed f32 pairs.
        f32x2 s0 = {0.f, 0.f}, s1 = {0.f, 0.f};
#pragma unroll
        for (int r = 0; r < 4; ++r) {
          s0 += (f32x2){aC[2 * r],     aC[2 * r + 1]} * (f32x2){aR[2 * r],     aR[2 * r + 1]};
          s1 += (f32x2){aC[2 * r + 8], aC[2 * r + 9]} * (f32x2){aR[2 * r + 8], aR[2 * r + 9]};
        }
        f32x2 t = s0 + s1;
        pout[dt] += t.x + t.y;
      }
    }
    // finish i-sum across lane halves; lane stores D = lane (coalesced).
    float v0 = pout[0] + __shfl_xor(pout[0], 32, 64);
    float v1 = pout[1] + __shfl_xor(pout[1], 32, 64);
    float val = h ? v1 : v0;
    size_t off = ((size_t)b * FDIM + n) * DDIM + lane;
    if (FINAL) ((float*)outp)[off] = val;
    else       ((unsigned short*)outp)[off] = f2bf(val);
  };

  // ---- software pipeline over n: load(n+1) issued a full iteration early ----
  loadn(mbA, atA, nBase + 0);
#pragma unroll 1
  for (int k = 0; k < NPB - 2; k += 2) {
    loadn(mbB, atB, nBase + k + 1);
    compute(mbA, atA, nBase + k);
    loadn(mbA, atA, nBase + k + 2);
    compute(mbB, atB, nBase + k + 1);
  }
  loadn(mbB, atB, nBase + NPB - 1);
  compute(mbA, atA, nBase + NPB - 2);
  compute(mbB, atB, nBase + NPB - 1);
}

extern "C" void kernel_launch(void* const* d_in, const int* in_sizes, int n_in,
                              void* d_out, int out_size, void* d_ws, size_t ws_size,
                              hipStream_t stream) {
  const float* inputs = (const float*)d_in[0];  // [2048,40,64]
  const float* W      = (const float*)d_in[1];  // [3,40,64,64]
  const float* alpha  = (const float*)d_in[2];  // [3,40,40,40]
  const float* h      = (const float*)d_in[3];  // [3,40,64,1]

  char* ws = (char*)d_ws;
  const size_t S   = (size_t)BATCH * FDIM * DDIM * 2;   // 10.49 MB bf16 buffer
  const size_t ST  = (size_t)BATCH * DDIM * FPAD * 2;   // 12.58 MB B0T
  unsigned short* Bi1 = (unsigned short*)(ws);
  unsigned short* Bi2 = (unsigned short*)(ws + S);
  unsigned short* B0b = (unsigned short*)(ws + 2 * S);
  unsigned short* B0T = (unsigned short*)(ws + 3 * S);
  unsigned short* Mb  = (unsigned short*)(ws + 3 * S + ST);
  unsigned short* ATb = (unsigned short*)(ws + 3 * S + ST + (size_t)LAY * FDIM * DDIM * DDIM * 2);

  prep_b_k<<<BATCH, 256, 0, stream>>>(inputs, B0b, B0T);
  const int nPrep4 = (LAY * FDIM * DDIM * DDIM + LAY * FDIM * IPAD * FPAD) / 4;
  prep_k<<<(nPrep4 + 255) / 256, 256, 0, stream>>>(W, h, alpha, Mb, ATb);

  dim3 grid(BATCH / 4 * NSPL), blk(256);   // 2048 blocks, 4 waves each (1 b/wave)
  const size_t mL = (size_t)FDIM * DDIM * DDIM;
  const size_t aL = (size_t)FDIM * IPAD * FPAD;
  layer_k<false><<<grid, blk, 0, stream>>>(B0b, B0T, Mb, ATb, Bi1);
  layer_k<false><<<grid, blk, 0, stream>>>(Bi1, B0T, Mb + mL, ATb + aL, Bi2);
  layer_k<true ><<<grid, blk, 0, stream>>>(Bi2, B0T, Mb + 2 * mL, ATb + 2 * aL, d_out);
}

// Round 2
// 261.585 us; speedup vs baseline: 1.3805x; 1.3805x over previous
//
#include <hip/hip_runtime.h>

// GeneralizedInteractionNet on MI355X (gfx950). R11: R9 structure + 4-way
// MFMA chain interleave.
//
// Per layer:  M[n,D,d] = W[n,D,d]*h[n,d]
//   GEMM1: C[b,i,D] = sum_d Bi[b,i,d] * M[n,D,d]
//   GEMM2: R[b,i,D] = sum_f AT[n,i,f] * B0T[b,D,f]^T
//   out[b,n,D] = sum_i C[b,i,D]*R[b,i,D]
// i padded 40->64 (2 row tiles of 32); f padded 40->48 (3 K-steps of 16).
// Padding garbage annihilated by exact zeros in AT (rows i>=40, cols f>=40).
//
// History:
//  R9 (263 us): b2=2, 2 waves/block, direct-from-L2 frags. MfmaUtil 39%.
//  R10 (361 us, FAILED): b2=1 + "register double-buffer" — VGPR_Count=112
//    proves the compiler re-sank the prefetch loads (pure loads, nothing
//    pinned them); ILP halved (1 chain vs 2). Reverted.
//  R11 theory: real per-wave regs = 108 VGPR + ~64 AGPR (f32x16 accs; unified
//    file) = ~172 -> 2 waves/SIMD (matches 17-20% occupancy). All structures
//    plateau at 40-46% MfmaUtil because only TWO accumulator chains are in
//    flight at any time (aC0/aC1 phase, then aR0/aR1 phase): 2 chains x 32cy
//    issue / ~130cy dep latency ~= 50% fill, no TLP slack at 2 waves/SIMD.
//    Fix: round-robin all FOUR independent chains in one ks loop (dep
//    distance 2->4 MFMAs) at zero register cost. setprio(1) around the MFMA
//    cluster (barrier-free independent waves = m191-positive regime).
//  Prep: single merged launch; B0T built via per-b padded-LDS transpose
//    (coalesced both ways) instead of stride-256B scalar gathers.

typedef __bf16 bf16x8 __attribute__((ext_vector_type(8)));
typedef float  f32x16 __attribute__((ext_vector_type(16)));
typedef unsigned short us4 __attribute__((ext_vector_type(4)));

constexpr int BATCH = 2048;
constexpr int FDIM  = 40;
constexpr int DDIM  = 64;
constexpr int LAY   = 3;
constexpr int IPAD  = 64;   // i padded: 2 row-tiles of 32
constexpr int FPAD  = 48;   // f padded: 3 K-steps of 16
constexpr int NSPL  = 4;    // n-loop split across 4 blocks
constexpr int NPB   = FDIM / NSPL;    // 10 n per block

__device__ __forceinline__ unsigned short f2bf(float f) {
  union { float f; unsigned u; } v; v.f = f;
  unsigned r = v.u + 0x7fff + ((v.u >> 16) & 1);   // round-to-nearest-even
  return (unsigned short)(r >> 16);
}

// Single prep launch, role by blockIdx.x:
//  blocks [0, BATCH):       B0b[b,f,d] = bf16(inputs) (coalesced passthrough)
//                           B0T[b,d,f48] = bf16(inputs[b,f,d]) via LDS transpose
//  blocks [BATCH, BATCH+840): M[l,n,D,d] = W*h; AT[l,n,i64,f48] = alpha[l,f,i,n]
__global__ __launch_bounds__(256) void prep_all(
    const float* __restrict__ inputs, const float* __restrict__ W,
    const float* __restrict__ h, const float* __restrict__ alpha,
    unsigned short* __restrict__ B0b, unsigned short* __restrict__ B0T,
    unsigned short* __restrict__ M, unsigned short* __restrict__ AT) {
  __shared__ float lds[FDIM][DDIM + 1];
  if (blockIdx.x < BATCH) {
    const int b = blockIdx.x;
    const float* src = inputs + (size_t)b * FDIM * DDIM;
    // 40*64 = 2560 floats = 640 float4; coalesced load, direct bf16 store.
    for (int cch = threadIdx.x; cch < FDIM * DDIM / 4; cch += 256) {
      float4 v = reinterpret_cast<const float4*>(src)[cch];
      int e = cch * 4;
      int f = e >> 6, d = e & 63;
      lds[f][d] = v.x; lds[f][d + 1] = v.y; lds[f][d + 2] = v.z; lds[f][d + 3] = v.w;
      us4 o = { f2bf(v.x), f2bf(v.y), f2bf(v.z), f2bf(v.w) };
      reinterpret_cast<us4*>(B0b + (size_t)b * FDIM * DDIM)[cch] = o;
    }
    __syncthreads();
    // B0T[b][d][f48]: 64*48 ushort = 768 us4 chunks; contiguous 8B stores.
    for (int cch = threadIdx.x; cch < DDIM * FPAD / 4; cch += 256) {
      int f4 = cch % (FPAD / 4);
      int d  = cch / (FPAD / 4);
      us4 o = {0, 0, 0, 0};
      if (f4 < FDIM / 4) {
        int f = f4 * 4;
        o[0] = f2bf(lds[f][d]);     o[1] = f2bf(lds[f + 1][d]);
        o[2] = f2bf(lds[f + 2][d]); o[3] = f2bf(lds[f + 3][d]);
      }
      reinterpret_cast<us4*>(B0T + (size_t)b * DDIM * FPAD)[cch] = o;
    }
    return;
  }
  int j = (blockIdx.x - BATCH) * 256 + threadIdx.x;
  const int nM4 = LAY * FDIM * DDIM * DDIM / 4;    // 122880
  const int nA4 = LAY * FDIM * IPAD * FPAD / 4;    // 92160
  if (j < nM4) {
    int e  = j * 4;
    int d  = e & 63;
    int ln = e >> 12;
    float4 wv = *reinterpret_cast<const float4*>(W + e);
    float4 hv = *reinterpret_cast<const float4*>(h + ln * DDIM + d);
    us4 o = { f2bf(wv.x * hv.x), f2bf(wv.y * hv.y), f2bf(wv.z * hv.z), f2bf(wv.w * hv.w) };
    *reinterpret_cast<us4*>(M + e) = o;
    return;
  }
  j -= nM4;
  if (j >= nA4) return;
  {
    int e  = j * 4;
    int f  = e % FPAD;
    int ii = (e / FPAD) % IPAD;
    int n  = (e / (FPAD * IPAD)) % FDIM;
    int l  = e / (FPAD * IPAD * FDIM);
    us4 o = {0, 0, 0, 0};
    if (ii < FDIM) {
#pragma unroll
      for (int k = 0; k < 4; ++k)
        if (f + k < FDIM)
          o[k] = f2bf(alpha[(((size_t)l * FDIM + f + k) * FDIM + ii) * FDIM + n]);
    }
    *reinterpret_cast<us4*>(AT + e) = o;
  }
}

// mfma_f32_32x32x16_bf16 conventions:
//   A[m=lane&31][k=8*(lane>>5)+j]  B[k=8*(lane>>5)+j][col=lane&31]
//   C/D: col=lane&31, row=(reg&3)+8*(reg>>2)+4*(lane>>5)   [HW-verified]
template <bool FINAL>
__global__ __launch_bounds__(128, 2) void layer_k(
    const unsigned short* __restrict__ Bi,   // bf16 [B][40][64] (prev layer / B0b)
    const unsigned short* __restrict__ B0T,  // bf16 [B][64][48]
    const unsigned short* __restrict__ Mt,   // [40][64][64] bf16
    const unsigned short* __restrict__ ATt,  // [40][64][48] bf16 zero-padded
    void* __restrict__ outp)                 // bf16 intermediate or f32 final
{
  const int tid  = threadIdx.x;
  const int lane = tid & 63;
  const int w    = tid >> 6;                  // wave in block (0,1)
  const int c    = lane & 31;
  const int h    = lane >> 5;
  const int bg   = blockIdx.x >> 2;           // 512 b-groups of 4 b
  const int nBase = (blockIdx.x & 3) * NPB;   // this block's n range
  const int bb   = bg * 4 + w * 2;            // wave's first batch element

  // ---- wave-constant register fragments (loaded once, reused over 10 n) ----
  // aBi[b2][it][ks]: GEMM1 A (rows i, k=d); rows>=40 clamped (killed by R=0).
  bf16x8 aBi[2][2][4];
#pragma unroll
  for (int b2 = 0; b2 < 2; ++b2)
#pragma unroll
    for (int it = 0; it < 2; ++it) {
      int row = it * 32 + c; if (row > FDIM - 1) row = FDIM - 1;
#pragma unroll
      for (int ks = 0; ks < 4; ++ks)
        aBi[b2][it][ks] = *reinterpret_cast<const bf16x8*>(
            Bi + ((size_t)(bb + b2) * FDIM + row) * DDIM + ks * 16 + h * 8);
    }

  // bT[b2][dt][ks]: GEMM2 B = B0T[b][D][f], contiguous 16B per lane.
  bf16x8 bT[2][2][3];
#pragma unroll
  for (int b2 = 0; b2 < 2; ++b2)
#pragma unroll
    for (int dt = 0; dt < 2; ++dt)
#pragma unroll
      for (int ks = 0; ks < 3; ++ks)
        bT[b2][dt][ks] = *reinterpret_cast<const bf16x8*>(
            B0T + ((size_t)(bb + b2) * DDIM + dt * 32 + c) * FPAD + ks * 16 + h * 8);

  for (int ln = 0; ln < NPB; ++ln) {
    const int n = nBase + ln;
    const unsigned short* Mn = Mt  + n * (DDIM * DDIM);
    const unsigned short* An = ATt + n * (IPAD * FPAD);

    // Per-n operands straight from L2 (M/AT are L2-resident: 573 KB/layer).
    // mb[dt][ks]: GEMM1 B-frag. B[k=d][col=D] = M[D][d]: lane (c,h) reads
    // row D = dt*32+c, bytes [ks*32 + h*16, +16) -- contiguous b128.
    bf16x8 mb[2][4];
#pragma unroll
    for (int dt = 0; dt < 2; ++dt)
#pragma unroll
      for (int ks = 0; ks < 4; ++ks)
        mb[dt][ks] = *reinterpret_cast<const bf16x8*>(
            Mn + (dt * 32 + c) * DDIM + ks * 16 + h * 8);

    // at[it][ks]: GEMM2 A-frag. A[m=i][k=f]: row i = it*32+c, contiguous b128.
    bf16x8 at[2][3];
#pragma unroll
    for (int it = 0; it < 2; ++it)
#pragma unroll
      for (int ks = 0; ks < 3; ++ks)
        at[it][ks] = *reinterpret_cast<const bf16x8*>(
            An + (it * 32 + c) * FPAD + ks * 16 + h * 8);

    float pout[2][2] = {{0.f, 0.f}, {0.f, 0.f}};   // [b2][dt]

#pragma unroll
    for (int it = 0; it < 2; ++it) {
#pragma unroll
      for (int dt = 0; dt < 2; ++dt) {
        // FOUR independent accumulator chains (b2 x {C,R}) round-robined:
        // dep distance = 4 MFMAs (~128cy of issue) vs the 2-chain phases of
        // R5/R9 (~64cy) that capped fill at ~50%.
        f32x16 aC0 = {0,0,0,0,0,0,0,0,0,0,0,0,0,0,0,0};
        f32x16 aC1 = {0,0,0,0,0,0,0,0,0,0,0,0,0,0,0,0};
        f32x16 aR0 = {0,0,0,0,0,0,0,0,0,0,0,0,0,0,0,0};
        f32x16 aR1 = {0,0,0,0,0,0,0,0,0,0,0,0,0,0,0,0};
        __builtin_amdgcn_s_setprio(1);
#pragma unroll
        for (int ks = 0; ks < 3; ++ks) {
          aC0 = __builtin_amdgcn_mfma_f32_32x32x16_bf16(aBi[0][it][ks], mb[dt][ks], aC0, 0, 0, 0);
          aC1 = __builtin_amdgcn_mfma_f32_32x32x16_bf16(aBi[1][it][ks], mb[dt][ks], aC1, 0, 0, 0);
          aR0 = __builtin_amdgcn_mfma_f32_32x32x16_bf16(at[it][ks], bT[0][dt][ks], aR0, 0, 0, 0);
          aR1 = __builtin_amdgcn_mfma_f32_32x32x16_bf16(at[it][ks], bT[1][dt][ks], aR1, 0, 0, 0);
        }
        aC0 = __builtin_amdgcn_mfma_f32_32x32x16_bf16(aBi[0][it][3], mb[dt][3], aC0, 0, 0, 0);
        aC1 = __builtin_amdgcn_mfma_f32_32x32x16_bf16(aBi[1][it][3], mb[dt][3], aC1, 0, 0, 0);
        __builtin_amdgcn_s_setprio(0);
        // Combine: 4 independent partial chains per b2 (depth 4, not 16).
        {
          float t0 = 0.f, t1 = 0.f, t2 = 0.f, t3 = 0.f;
#pragma unroll
          for (int r = 0; r < 4; ++r) {
            t0 += aC0[r] * aR0[r];         t1 += aC0[r + 4] * aR0[r + 4];
            t2 += aC0[r + 8] * aR0[r + 8]; t3 += aC0[r + 12] * aR0[r + 12];
          }
          pout[0][dt] += (t0 + t1) + (t2 + t3);
        }
        {
          float t0 = 0.f, t1 = 0.f, t2 = 0.f, t3 = 0.f;
#pragma unroll
          for (int r = 0; r < 4; ++r) {
            t0 += aC1[r] * aR1[r];         t1 += aC1[r + 4] * aR1[r + 4];
            t2 += aC1[r + 8] * aR1[r + 8]; t3 += aC1[r + 12] * aR1[r + 12];
          }
          pout[1][dt] += (t0 + t1) + (t2 + t3);
        }
      }
    }

    // finish i-sum across lane halves; lane stores D = h-selected half:
    // D = dt*32 + c with dt = h, i.e. D = lane (coalesced).
#pragma unroll
    for (int b2 = 0; b2 < 2; ++b2) {
      float v0 = pout[b2][0] + __shfl_xor(pout[b2][0], 32, 64);
      float v1 = pout[b2][1] + __shfl_xor(pout[b2][1], 32, 64);
      float val = h ? v1 : v0;
      size_t off = ((size_t)(bb + b2) * FDIM + n) * DDIM + lane;
      if (FINAL) ((float*)outp)[off] = val;
      else       ((unsigned short*)outp)[off] = f2bf(val);
    }
  }
}

extern "C" void kernel_launch(void* const* d_in, const int* in_sizes, int n_in,
                              void* d_out, int out_size, void* d_ws, size_t ws_size,
                              hipStream_t stream) {
  const float* inputs = (const float*)d_in[0];  // [2048,40,64]
  const float* W      = (const float*)d_in[1];  // [3,40,64,64]
  const float* alpha  = (const float*)d_in[2];  // [3,40,40,40]
  const float* h      = (const float*)d_in[3];  // [3,40,64,1]

  char* ws = (char*)d_ws;
  const size_t S   = (size_t)BATCH * FDIM * DDIM * 2;   // 10.49 MB bf16 buffer
  const size_t ST  = (size_t)BATCH * DDIM * FPAD * 2;   // 12.58 MB B0T
  unsigned short* Bi1 = (unsigned short*)(ws);
  unsigned short* Bi2 = (unsigned short*)(ws + S);
  unsigned short* B0b = (unsigned short*)(ws + 2 * S);
  unsigned short* B0T = (unsigned short*)(ws + 3 * S);
  unsigned short* Mb  = (unsigned short*)(ws + 3 * S + ST);
  unsigned short* ATb = (unsigned short*)(ws + 3 * S + ST + (size_t)LAY * FDIM * DDIM * DDIM * 2);

  const int nPrep4 = (LAY * FDIM * DDIM * DDIM + LAY * FDIM * IPAD * FPAD) / 4;
  const int prepBlocks = BATCH + (nPrep4 + 255) / 256;   // 2048 + 840
  prep_all<<<prepBlocks, 256, 0, stream>>>(inputs, W, h, alpha, B0b, B0T, Mb, ATb);

  dim3 grid(BATCH / 4 * NSPL), blk(128);   // 2048 blocks, 2 waves each
  const size_t mL = (size_t)FDIM * DDIM * DDIM;
  const size_t aL = (size_t)FDIM * IPAD * FPAD;
  layer_k<false><<<grid, blk, 0, stream>>>(B0b, B0T, Mb, ATb, Bi1);
  layer_k<false><<<grid, blk, 0, stream>>>(Bi1, B0T, Mb + mL, ATb + aL, Bi2);
  layer_k<true ><<<grid, blk, 0, stream>>>(Bi2, B0T, Mb + 2 * mL, ATb + 2 * aL, d_out);
}

// Round 3
// 235.028 us; speedup vs baseline: 1.5365x; 1.1130x over previous
//
#include <hip/hip_runtime.h>

// GeneralizedInteractionNet on MI355X (gfx950). R12: LDS-chunked M/AT staging,
// conflict-free swizzle, wave n-stagger, XCD-grouped blocks.
//
// Per layer:  M[n,D,d] = W[n,D,d]*h[n,d]
//   GEMM1: C[b,i,D] = sum_d Bi[b,i,d] * M[n,D,d]
//   GEMM2: R[b,i,D] = sum_f AT[n,i,f] * B0T[b,D,f]^T
//   out[b,n,D] = sum_i C[b,i,D]*R[b,i,D]
// i padded 40->64 (2 row tiles of 32); f padded 40->48 (3 K-steps of 16).
//
// History:
//  R9 (263us): direct-from-L2 per-n frags, 2 waves/block. MfmaUtil 39%.
//  R10 (361us FAILED): compiler sank the register prefetch; ILP halved.
//  R11 (261us): 4-way chain interleave -> 42.6%, noise. Latency-between-chains
//    refuted as the stall. Arithmetic: wave spends ~8400cy/n-iter, only
//    1810 MFMA + ~900 VALU busy -> ~5700cy stalled. Suspects: (a) mb/at
//    global loads miss L2 (streams evict M/AT; FETCH=2x ideal from ns-sibling
//    blocks on different XCDs), (b) phase-locked convoy of the 2 waves/SIMD.
//  R12: 8-wave blocks; M/AT staged per-2n-chunk into LDS (dbuf, ONE barrier
//    per 2n, T14 load-early/write-late). M rows XOR-swizzled (chunk^=row&7),
//    AT rows padded 96->112B: both 4-way max on ds_read_b128 (vs 32-way for
//    linear 128B rows -- likely R5's hidden cost). Waves stagger n-order by
//    parity to decorrelate pipe gaps. Block-id swizzle: 4 ns-siblings of a
//    b-group co-XCD -> Bi/B0T fetched once per L2. Acc = 2 live chains
//    (b2-sequential per tile) to hold regs ~235.

typedef __bf16 bf16x8 __attribute__((ext_vector_type(8)));
typedef float  f32x16 __attribute__((ext_vector_type(16)));
typedef unsigned short us4 __attribute__((ext_vector_type(4)));

constexpr int BATCH = 2048;
constexpr int FDIM  = 40;
constexpr int DDIM  = 64;
constexpr int LAY   = 3;
constexpr int IPAD  = 64;   // i padded: 2 row-tiles of 32
constexpr int FPAD  = 48;   // f padded: 3 K-steps of 16
constexpr int NSPL  = 4;    // n-loop split across 4 blocks
constexpr int NPB   = FDIM / NSPL;    // 10 n per block
constexpr int BPB   = 16;   // b per block (8 waves x b2=2)
constexpr int NCH   = NPB / 2;        // 5 chunks of 2 n

__device__ __forceinline__ unsigned short f2bf(float f) {
  union { float f; unsigned u; } v; v.f = f;
  unsigned r = v.u + 0x7fff + ((v.u >> 16) & 1);   // round-to-nearest-even
  return (unsigned short)(r >> 16);
}

// Single prep launch, role by blockIdx.x:
//  blocks [0, BATCH):       B0b[b,f,d] = bf16(inputs) (coalesced passthrough)
//                           B0T[b,d,f48] = bf16(inputs[b,f,d]) via LDS transpose
//  blocks [BATCH, BATCH+840): M[l,n,D,d] = W*h; AT[l,n,i64,f48] = alpha[l,f,i,n]
__global__ __launch_bounds__(256) void prep_all(
    const float* __restrict__ inputs, const float* __restrict__ W,
    const float* __restrict__ h, const float* __restrict__ alpha,
    unsigned short* __restrict__ B0b, unsigned short* __restrict__ B0T,
    unsigned short* __restrict__ M, unsigned short* __restrict__ AT) {
  __shared__ float lds[FDIM][DDIM + 1];
  if (blockIdx.x < BATCH) {
    const int b = blockIdx.x;
    const float* src = inputs + (size_t)b * FDIM * DDIM;
    for (int cch = threadIdx.x; cch < FDIM * DDIM / 4; cch += 256) {
      float4 v = reinterpret_cast<const float4*>(src)[cch];
      int e = cch * 4;
      int f = e >> 6, d = e & 63;
      lds[f][d] = v.x; lds[f][d + 1] = v.y; lds[f][d + 2] = v.z; lds[f][d + 3] = v.w;
      us4 o = { f2bf(v.x), f2bf(v.y), f2bf(v.z), f2bf(v.w) };
      reinterpret_cast<us4*>(B0b + (size_t)b * FDIM * DDIM)[cch] = o;
    }
    __syncthreads();
    for (int cch = threadIdx.x; cch < DDIM * FPAD / 4; cch += 256) {
      int f4 = cch % (FPAD / 4);
      int d  = cch / (FPAD / 4);
      us4 o = {0, 0, 0, 0};
      if (f4 < FDIM / 4) {
        int f = f4 * 4;
        o[0] = f2bf(lds[f][d]);     o[1] = f2bf(lds[f + 1][d]);
        o[2] = f2bf(lds[f + 2][d]); o[3] = f2bf(lds[f + 3][d]);
      }
      reinterpret_cast<us4*>(B0T + (size_t)b * DDIM * FPAD)[cch] = o;
    }
    return;
  }
  int j = (blockIdx.x - BATCH) * 256 + threadIdx.x;
  const int nM4 = LAY * FDIM * DDIM * DDIM / 4;    // 122880
  const int nA4 = LAY * FDIM * IPAD * FPAD / 4;    // 92160
  if (j < nM4) {
    int e  = j * 4;
    int d  = e & 63;
    int ln = e >> 12;
    float4 wv = *reinterpret_cast<const float4*>(W + e);
    float4 hv = *reinterpret_cast<const float4*>(h + ln * DDIM + d);
    us4 o = { f2bf(wv.x * hv.x), f2bf(wv.y * hv.y), f2bf(wv.z * hv.z), f2bf(wv.w * hv.w) };
    *reinterpret_cast<us4*>(M + e) = o;
    return;
  }
  j -= nM4;
  if (j >= nA4) return;
  {
    int e  = j * 4;
    int f  = e % FPAD;
    int ii = (e / FPAD) % IPAD;
    int n  = (e / (FPAD * IPAD)) % FDIM;
    int l  = e / (FPAD * IPAD * FDIM);
    us4 o = {0, 0, 0, 0};
    if (ii < FDIM) {
#pragma unroll
      for (int k = 0; k < 4; ++k)
        if (f + k < FDIM)
          o[k] = f2bf(alpha[(((size_t)l * FDIM + f + k) * FDIM + ii) * FDIM + n]);
    }
    *reinterpret_cast<us4*>(AT + e) = o;
  }
}

// mfma_f32_32x32x16_bf16 conventions:
//   A[m=lane&31][k=8*(lane>>5)+j]  B[k=8*(lane>>5)+j][col=lane&31]
//   C/D: col=lane&31, row=(reg&3)+8*(reg>>2)+4*(lane>>5)   [HW-verified]
template <bool FINAL>
__global__ __launch_bounds__(512, 2) void layer_k(
    const unsigned short* __restrict__ Bi,   // bf16 [B][40][64] (prev layer / B0b)
    const unsigned short* __restrict__ B0T,  // bf16 [B][64][48]
    const unsigned short* __restrict__ Mt,   // [40][64][64] bf16
    const unsigned short* __restrict__ ATt,  // [40][64][48] bf16 zero-padded
    void* __restrict__ outp)                 // bf16 intermediate or f32 final
{
  // LDS: double-buffered 2-n chunks. M rows 128B XOR-swizzled (16B chunk index
  // ^= row&7 -> 4-way max on frag reads). AT rows padded 96->112B (stride 28
  // words -> natural 4-way). Total 60 KB (<64 KB, no API games).
  __shared__ unsigned short smM[2][2][64 * 64];
  __shared__ unsigned short smA[2][2][64 * 56];

  const int tid  = threadIdx.x;
  const int lane = tid & 63;
  const int w    = tid >> 6;                  // wave 0..7
  const int c    = lane & 31;
  const int h    = lane >> 5;

  // XCD grouping: physical dispatch d -> logical L = (d&7)*64 + d>>3, so each
  // XCD (consecutive-d round-robin) owns 64 consecutive L = 16 b-groups with
  // ALL 4 ns-splits -> Bi/B0T of a b-group fetched into exactly one L2.
  const int L  = (blockIdx.x & 7) * 64 + (blockIdx.x >> 3);
  const int bg = L >> 2;                      // 0..127
  const int ns = L & 3;                       // n-quarter
  const int nBase = ns * NPB;
  const int bb = bg * BPB + w * 2;            // wave's first batch element

  // ---- wave-constant register fragments (loaded once, reused over 10 n) ----
  bf16x8 aBi[2][2][4];
#pragma unroll
  for (int b2 = 0; b2 < 2; ++b2)
#pragma unroll
    for (int it = 0; it < 2; ++it) {
      int row = it * 32 + c; if (row > FDIM - 1) row = FDIM - 1;
#pragma unroll
      for (int ks = 0; ks < 4; ++ks)
        aBi[b2][it][ks] = *reinterpret_cast<const bf16x8*>(
            Bi + ((size_t)(bb + b2) * FDIM + row) * DDIM + ks * 16 + h * 8);
    }
  bf16x8 bT[2][2][3];
#pragma unroll
  for (int b2 = 0; b2 < 2; ++b2)
#pragma unroll
    for (int dt = 0; dt < 2; ++dt)
#pragma unroll
      for (int ks = 0; ks < 3; ++ks)
        bT[b2][dt][ks] = *reinterpret_cast<const bf16x8*>(
            B0T + ((size_t)(bb + b2) * DDIM + dt * 32 + c) * FPAD + ks * 16 + h * 8);

  // ---- staging helpers: chunk cc = 2 n of M (1024x16B) + AT (768x16B) ----
  auto stageL = [&](int cc, bf16x8 (&sM)[2], bf16x8 (&sA)[2]) {
#pragma unroll
    for (int r = 0; r < 2; ++r) {
      int k = tid + r * 512;                 // 0..1023
      int nn = k >> 9, rem = k & 511;
      int row = rem >> 3, c8 = rem & 7;
      sM[r] = *reinterpret_cast<const bf16x8*>(
          Mt + (size_t)(nBase + cc * 2 + nn) * (DDIM * DDIM) + row * 64 + c8 * 8);
    }
#pragma unroll
    for (int r = 0; r < 2; ++r) {
      int k = tid + r * 512;
      if (k < 768) {
        int nn = k / 384, rem = k % 384;
        int row = rem / 6, c6 = rem % 6;
        sA[r] = *reinterpret_cast<const bf16x8*>(
            ATt + (size_t)(nBase + cc * 2 + nn) * (IPAD * FPAD) + row * 48 + c6 * 8);
      }
    }
  };
  auto stageW = [&](int cc, const bf16x8 (&sM)[2], const bf16x8 (&sA)[2]) {
    int bs = cc & 1;
#pragma unroll
    for (int r = 0; r < 2; ++r) {
      int k = tid + r * 512;
      int nn = k >> 9, rem = k & 511;
      int row = rem >> 3, c8 = rem & 7;
      *reinterpret_cast<bf16x8*>(
          &smM[bs][nn][row * 64 + ((c8 ^ (row & 7)) * 8)]) = sM[r];
    }
#pragma unroll
    for (int r = 0; r < 2; ++r) {
      int k = tid + r * 512;
      if (k < 768) {
        int nn = k / 384, rem = k % 384;
        int row = rem / 6, c6 = rem % 6;
        *reinterpret_cast<bf16x8*>(&smA[bs][nn][row * 56 + c6 * 8]) = sA[r];
      }
    }
  };

  auto compute = [&](int nl, int bs) {       // nl in 0..9, buffer bs
    const int n  = nBase + nl;
    const int nn = nl & 1;
    const unsigned short* mL = &smM[bs][nn][0];
    const unsigned short* aL = &smA[bs][nn][0];
    // frag reads from LDS: 14 x ds_read_b128, 4-way max bank aliasing
    bf16x8 mb[2][4], at[2][3];
#pragma unroll
    for (int dt = 0; dt < 2; ++dt)
#pragma unroll
      for (int ks = 0; ks < 4; ++ks)
        mb[dt][ks] = *reinterpret_cast<const bf16x8*>(
            mL + (dt * 32 + c) * 64 + (((ks * 2 + h) ^ (c & 7)) * 8));
#pragma unroll
    for (int it = 0; it < 2; ++it)
#pragma unroll
      for (int ks = 0; ks < 3; ++ks)
        at[it][ks] = *reinterpret_cast<const bf16x8*>(
            aL + (it * 32 + c) * 56 + (ks * 2 + h) * 8);

    float pout[2][2] = {{0.f, 0.f}, {0.f, 0.f}};
#pragma unroll
    for (int it = 0; it < 2; ++it) {
#pragma unroll
      for (int dt = 0; dt < 2; ++dt) {
#pragma unroll
        for (int b2 = 0; b2 < 2; ++b2) {
          // 2 live chains (C,R round-robin); b2 sequential keeps acc at 32
          // regs; combine of b2=0 overlaps b2=1's MFMAs (independent accs).
          f32x16 aC = {0,0,0,0,0,0,0,0,0,0,0,0,0,0,0,0};
          f32x16 aR = {0,0,0,0,0,0,0,0,0,0,0,0,0,0,0,0};
          __builtin_amdgcn_s_setprio(1);
#pragma unroll
          for (int ks = 0; ks < 3; ++ks) {
            aC = __builtin_amdgcn_mfma_f32_32x32x16_bf16(aBi[b2][it][ks], mb[dt][ks], aC, 0, 0, 0);
            aR = __builtin_amdgcn_mfma_f32_32x32x16_bf16(at[it][ks], bT[b2][dt][ks], aR, 0, 0, 0);
          }
          aC = __builtin_amdgcn_mfma_f32_32x32x16_bf16(aBi[b2][it][3], mb[dt][3], aC, 0, 0, 0);
          __builtin_amdgcn_s_setprio(0);
          float t0 = 0.f, t1 = 0.f, t2 = 0.f, t3 = 0.f;
#pragma unroll
          for (int r = 0; r < 4; ++r) {
            t0 += aC[r] * aR[r];         t1 += aC[r + 4] * aR[r + 4];
            t2 += aC[r + 8] * aR[r + 8]; t3 += aC[r + 12] * aR[r + 12];
          }
          pout[b2][dt] += (t0 + t1) + (t2 + t3);
        }
      }
    }
#pragma unroll
    for (int b2 = 0; b2 < 2; ++b2) {
      float v0 = pout[b2][0] + __shfl_xor(pout[b2][0], 32, 64);
      float v1 = pout[b2][1] + __shfl_xor(pout[b2][1], 32, 64);
      float val = h ? v1 : v0;
      size_t off = ((size_t)(bb + b2) * FDIM + n) * DDIM + lane;
      if (FINAL) ((float*)outp)[off] = val;
      else       ((unsigned short*)outp)[off] = f2bf(val);
    }
  };

  // ---- main: dbuf chunks of 2 n; ONE barrier per chunk; T14 split ----
  {
    bf16x8 sM[2], sA[2];
    stageL(0, sM, sA);
    stageW(0, sM, sA);
  }
  __syncthreads();
#pragma unroll 1
  for (int cc = 0; cc < NCH; ++cc) {
    const int bs = cc & 1;
    const int nf = w & 1;                    // stagger: odd waves swap n order
    bf16x8 sM[2], sA[2];
    if (cc + 1 < NCH) stageL(cc + 1, sM, sA);   // issue loads early
    compute(cc * 2 + nf, bs);
    if (cc + 1 < NCH) stageW(cc + 1, sM, sA);   // LDS writes late (other buf)
    compute(cc * 2 + (nf ^ 1), bs);
    __syncthreads();
  }
}

extern "C" void kernel_launch(void* const* d_in, const int* in_sizes, int n_in,
                              void* d_out, int out_size, void* d_ws, size_t ws_size,
                              hipStream_t stream) {
  const float* inputs = (const float*)d_in[0];  // [2048,40,64]
  const float* W      = (const float*)d_in[1];  // [3,40,64,64]
  const float* alpha  = (const float*)d_in[2];  // [3,40,40,40]
  const float* h      = (const float*)d_in[3];  // [3,40,64,1]

  char* ws = (char*)d_ws;
  const size_t S   = (size_t)BATCH * FDIM * DDIM * 2;   // 10.49 MB bf16 buffer
  const size_t ST  = (size_t)BATCH * DDIM * FPAD * 2;   // 12.58 MB B0T
  unsigned short* Bi1 = (unsigned short*)(ws);
  unsigned short* Bi2 = (unsigned short*)(ws + S);
  unsigned short* B0b = (unsigned short*)(ws + 2 * S);
  unsigned short* B0T = (unsigned short*)(ws + 3 * S);
  unsigned short* Mb  = (unsigned short*)(ws + 3 * S + ST);
  unsigned short* ATb = (unsigned short*)(ws + 3 * S + ST + (size_t)LAY * FDIM * DDIM * DDIM * 2);

  const int nPrep4 = (LAY * FDIM * DDIM * DDIM + LAY * FDIM * IPAD * FPAD) / 4;
  const int prepBlocks = BATCH + (nPrep4 + 255) / 256;   // 2048 + 840
  prep_all<<<prepBlocks, 256, 0, stream>>>(inputs, W, h, alpha, B0b, B0T, Mb, ATb);

  dim3 grid(BATCH / BPB * NSPL), blk(512);   // 512 blocks, 8 waves, 16 b each
  const size_t mL = (size_t)FDIM * DDIM * DDIM;
  const size_t aL = (size_t)FDIM * IPAD * FPAD;
  layer_k<false><<<grid, blk, 0, stream>>>(B0b, B0T, Mb, ATb, Bi1);
  layer_k<false><<<grid, blk, 0, stream>>>(Bi1, B0T, Mb + mL, ATb + aL, Bi2);
  layer_k<true ><<<grid, blk, 0, stream>>>(Bi2, B0T, Mb + 2 * mL, ATb + 2 * aL, d_out);
}